// Round 14
// baseline (406.881 us; speedup 1.0000x reference)
//
#include <hip/hip_runtime.h>

#define SPR 128  // samples per ray

// Opaque f32 ops — immune to fast-math folding/reassociation.
__device__ __forceinline__ float fadd32(float a, float b) {
    float d; asm("v_add_f32 %0, %1, %2" : "=v"(d) : "v"(a), "v"(b)); return d;
}
__device__ __forceinline__ float fsub32(float a, float b) {
    float d; asm("v_sub_f32 %0, %1, %2" : "=v"(d) : "v"(a), "v"(b)); return d;
}
__device__ __forceinline__ float fmul32(float a, float b) {
    float d; asm("v_mul_f32 %0, %1, %2" : "=v"(d) : "v"(a), "v"(b)); return d;
}

// ---------------------------------------------------------------------------
// Emulating XLA's ReduceWindowRewriter cumsum (base_length=16), bit-exact:
//   level k: rows of 16; P = in-row left-fold prefix (small magnitude);
//   out[m] = fl(offset + P[m]),  offset(row q) = c_{k+1}[q-1]  (recursive,
//   exclusive via exact shift); top row (<16 elems) = plain left fold.
// Chains: w (= ws) and p (= fl32(ws*ts)).
// ---------------------------------------------------------------------------

// K1: heads + T1[m] = sum of 16-sample row m (both chains).
__global__ __launch_bounds__(256) void k1(
    const float* __restrict__ rgb_pred,
    const float* __restrict__ rgb_target,
    const float* __restrict__ opacity,
    const float* __restrict__ ws,
    const float* __restrict__ ts,
    float* __restrict__ out,
    float* __restrict__ T1w, float* __restrict__ T1p,
    int n_rays)
{
    const int tid  = blockIdx.x * blockDim.x + threadIdx.x;
    const int ray  = tid >> 6;
    const int lane = tid & 63;
    const int nrgb = 3 * n_rays;

    if (tid < nrgb) {
        float d = rgb_pred[tid] - rgb_target[tid];
        out[tid] = d * d + 1e-5f;
    }
    if (tid < n_rays) {
        float o = opacity[tid] + 1e-5f;
        out[nrgb + tid] = -0.001f * o * logf(o);
    }
    if (ray >= n_rays) return;

    const long base = (long)ray * SPR;
    const float2 w = ((const float2*)(ws + base))[lane];
    const float2 t = ((const float2*)(ts + base))[lane];

    const float p0 = fmul32(w.x, t.x);
    const float p1 = fmul32(w.y, t.y);

    float sw = fadd32(w.x, w.y);
    float sp = fadd32(p0, p1);
    // reduce within 8-lane group (16 samples) — small-mag association is
    // flip-safe (feeds exactly one big rounding above)
    sw = fadd32(sw, __shfl_xor(sw, 1)); sp = fadd32(sp, __shfl_xor(sp, 1));
    sw = fadd32(sw, __shfl_xor(sw, 2)); sp = fadd32(sp, __shfl_xor(sp, 2));
    sw = fadd32(sw, __shfl_xor(sw, 4)); sp = fadd32(sp, __shfl_xor(sp, 4));

    if ((lane & 7) == 0) {
        const long m = (long)ray * 8 + (lane >> 3);
        T1w[m] = sw; T1p[m] = sp;
    }
}

// K2: single block. Build T2..T5 (row sums), then offsets top-down:
// c6 = fold(T5); c5[m]=fl(c6[q-1]+fold T4); c4 from T3; c3 (rows) from T2
// with off=c4; c2 (rows) from T1 with off=c3. c2[m-1] is the offset for
// final level-1 row m.
__global__ __launch_bounds__(1024) void k2(
    const float* __restrict__ T1w, const float* __restrict__ T1p,
    float* __restrict__ c2w, float* __restrict__ c2p,
    float* __restrict__ T2w, float* __restrict__ T2p,
    float* __restrict__ c3w, float* __restrict__ c3p,
    float* __restrict__ T3w, float* __restrict__ T3p,
    float* __restrict__ c4w, float* __restrict__ c4p,
    float* __restrict__ T4w, float* __restrict__ T4p,
    float* __restrict__ c5w, float* __restrict__ c5p,
    float* __restrict__ T5w, float* __restrict__ T5p,
    float* __restrict__ c6w, float* __restrict__ c6p,
    int n1)
{
    const int tid = threadIdx.x;
    const int n2 = n1 >> 4, n3 = n2 >> 4, n4 = n3 >> 4, n5 = n4 >> 4;

    for (int m = tid; m < n2; m += 1024) {
        float aw = 0.0f, ap = 0.0f;
        for (int i = 0; i < 16; ++i) {
            aw = fadd32(aw, T1w[16 * m + i]); ap = fadd32(ap, T1p[16 * m + i]);
        }
        T2w[m] = aw; T2p[m] = ap;
    }
    __syncthreads();
    for (int m = tid; m < n3; m += 1024) {
        float aw = 0.0f, ap = 0.0f;
        for (int i = 0; i < 16; ++i) {
            aw = fadd32(aw, T2w[16 * m + i]); ap = fadd32(ap, T2p[16 * m + i]);
        }
        T3w[m] = aw; T3p[m] = ap;
    }
    __syncthreads();
    for (int m = tid; m < n4; m += 1024) {
        float aw = 0.0f, ap = 0.0f;
        for (int i = 0; i < 16; ++i) {
            aw = fadd32(aw, T3w[16 * m + i]); ap = fadd32(ap, T3p[16 * m + i]);
        }
        T4w[m] = aw; T4p[m] = ap;
    }
    __syncthreads();
    for (int m = tid; m < n5; m += 1024) {
        float aw = 0.0f, ap = 0.0f;
        for (int i = 0; i < 16; ++i) {
            aw = fadd32(aw, T4w[16 * m + i]); ap = fadd32(ap, T4p[16 * m + i]);
        }
        T5w[m] = aw; T5p[m] = ap;
    }
    __syncthreads();
    if (tid == 0) {  // c6: top row (< 16 elems): plain left-fold cumsum
        float aw = 0.0f, ap = 0.0f;
        for (int i = 0; i < n5; ++i) {
            aw = fadd32(aw, T5w[i]); ap = fadd32(ap, T5p[i]);
            c6w[i] = aw; c6p[i] = ap;
        }
    }
    __syncthreads();
    for (int m = tid; m < n4; m += 1024) {   // c5
        const int q = m >> 4;
        const float ow = q ? c6w[q - 1] : 0.0f;
        const float op = q ? c6p[q - 1] : 0.0f;
        float aw = 0.0f, ap = 0.0f;
        for (int i = 16 * q; i <= m; ++i) {
            aw = fadd32(aw, T4w[i]); ap = fadd32(ap, T4p[i]);
        }
        c5w[m] = fadd32(ow, aw); c5p[m] = fadd32(op, ap);
    }
    __syncthreads();
    for (int m = tid; m < n3; m += 1024) {   // c4
        const int q = m >> 4;
        const float ow = q ? c5w[q - 1] : 0.0f;
        const float op = q ? c5p[q - 1] : 0.0f;
        float aw = 0.0f, ap = 0.0f;
        for (int i = 16 * q; i <= m; ++i) {
            aw = fadd32(aw, T3w[i]); ap = fadd32(ap, T3p[i]);
        }
        c4w[m] = fadd32(ow, aw); c4p[m] = fadd32(op, ap);
    }
    __syncthreads();
    for (int q = tid; q < n3; q += 1024) {   // c3: rows of T2
        const float ow = q ? c4w[q - 1] : 0.0f;
        const float op = q ? c4p[q - 1] : 0.0f;
        float aw = 0.0f, ap = 0.0f;
        for (int i = 0; i < 16; ++i) {
            aw = fadd32(aw, T2w[16 * q + i]); ap = fadd32(ap, T2p[16 * q + i]);
            c3w[16 * q + i] = fadd32(ow, aw);
            c3p[16 * q + i] = fadd32(op, ap);
        }
    }
    __syncthreads();
    for (int q = tid; q < n2; q += 1024) {   // c2: rows of T1
        const float ow = q ? c3w[q - 1] : 0.0f;
        const float op = q ? c3p[q - 1] : 0.0f;
        float aw = 0.0f, ap = 0.0f;
        for (int i = 0; i < 16; ++i) {
            aw = fadd32(aw, T1w[16 * q + i]); ap = fadd32(ap, T1p[16 * q + i]);
            c2w[16 * q + i] = fadd32(ow, aw);
            c2p[16 * q + i] = fadd32(op, ap);
        }
    }
}

// K3: loss. c_j = fl(c2[m-1] + P1_j) (m = global 16-row index); base =
// c at 128r-1 = fl(c2[8r-2] + T1[8r-1]); ws_scan = fl(c_j - base).
__global__ __launch_bounds__(256) void k3(
    const float* __restrict__ ws,
    const float* __restrict__ ts,
    const float* __restrict__ deltas,
    const float* __restrict__ T1w, const float* __restrict__ T1p,
    const float* __restrict__ c2w, const float* __restrict__ c2p,
    float* __restrict__ out,
    int n_rays)
{
    const int tid  = blockIdx.x * blockDim.x + threadIdx.x;
    const int ray  = tid >> 6;
    const int lane = tid & 63;
    const int gl   = lane & 7;     // lane within 16-sample row
    if (ray >= n_rays) return;

    const long base = (long)ray * SPR;
    const float2 w  = ((const float2*)(ws + base))[lane];
    const float2 t  = ((const float2*)(ts + base))[lane];
    const float2 dl = ((const float2*)(deltas + base))[lane];

    const float p0 = fmul32(w.x, t.x);
    const float p1 = fmul32(w.y, t.y);

    // small-mag in-row prefix (pair scan over 8 lanes)
    const float sw = fadd32(w.x, w.y);
    const float sp = fadd32(p0, p1);
    float iw = sw, ip = sp;
    #pragma unroll
    for (int off = 1; off < 8; off <<= 1) {
        const float a = __shfl_up(iw, off);
        const float b = __shfl_up(ip, off);
        if (gl >= off) { iw = fadd32(iw, a); ip = fadd32(ip, b); }
    }
    const float iwp = __shfl_up(iw, 1);
    const float ipp = __shfl_up(ip, 1);
    const float exw = (gl == 0) ? 0.0f : iwp;
    const float exq = (gl == 0) ? 0.0f : ipp;

    const float P0w = fadd32(exw, w.x);   // in-row prefix at sample 2l
    const float P0p = fadd32(exq, p0);
    const float P1w = iw;                 // at sample 2l+1
    const float P1p = ip;

    // offset for this 16-row: c2[m-1]
    const long m = (long)ray * 8 + (lane >> 3);
    const float ow = (m > 0) ? c2w[m - 1] : 0.0f;
    const float op = (m > 0) ? c2p[m - 1] : 0.0f;

    const float cw0 = fadd32(ow, P0w), cw1 = fadd32(ow, P1w);
    const float cp0 = fadd32(op, P0p), cp1 = fadd32(op, P1p);

    // base = c[128r-1]
    float baseW = 0.0f, baseP = 0.0f;
    if (ray > 0) {
        const long mb = (long)ray * 8 - 1;
        const float bw = c2w[mb - 1];   // mb >= 7, safe
        const float bp = c2p[mb - 1];
        baseW = fadd32(bw, T1w[mb]);
        baseP = fadd32(bp, T1p[mb]);
    }

    const float Q0 = fsub32(cw0, baseW);
    const float Q1 = fsub32(cw1, baseW);
    const float R0 = fsub32(cp0, baseP);
    const float R1 = fsub32(cp1, baseP);

    float contrib = 2.0f * w.x * (t.x * Q0 - R0) + w.x * w.x * dl.x / 3.0f
                  + 2.0f * w.y * (t.y * Q1 - R1) + w.y * w.y * dl.y / 3.0f;

    #pragma unroll
    for (int off = 32; off > 0; off >>= 1)
        contrib += __shfl_xor(contrib, off);

    if (lane == 0) out[(long)4 * n_rays + ray] = 0.001f * contrib;
}

// ---------------------------------------------------------------------------
extern "C" void kernel_launch(void* const* d_in, const int* in_sizes, int n_in,
                              void* d_out, int out_size, void* d_ws, size_t ws_size,
                              hipStream_t stream) {
    const float* rgb_pred   = (const float*)d_in[0];
    const float* rgb_target = (const float*)d_in[1];
    const float* opacity    = (const float*)d_in[2];
    const float* ws         = (const float*)d_in[3];
    const float* deltas     = (const float*)d_in[4];
    const float* ts         = (const float*)d_in[5];
    // d_in[6] = rays_a; structure fixed: ray r -> samples [r*128, r*128+128)

    float* out = (float*)d_out;
    const int n_rays = in_sizes[2];

    const int n1 = n_rays * 8;          // 16-sample rows
    const int n2 = n1 >> 4, n3 = n2 >> 4, n4 = n3 >> 4, n5 = n4 >> 4;

    float* f = (float*)d_ws;
    float* T1w = f;            f += n1;
    float* T1p = f;            f += n1;
    float* c2w = f;            f += n1;
    float* c2p = f;            f += n1;
    float* T2w = f;            f += n2;
    float* T2p = f;            f += n2;
    float* c3w = f;            f += n2;
    float* c3p = f;            f += n2;
    float* T3w = f;            f += n3;
    float* T3p = f;            f += n3;
    float* c4w = f;            f += n3;
    float* c4p = f;            f += n3;
    float* T4w = f;            f += n4;
    float* T4p = f;            f += n4;
    float* c5w = f;            f += n4;
    float* c5p = f;            f += n4;
    float* T5w = f;            f += n5;
    float* T5p = f;            f += n5;
    float* c6w = f;            f += n5;
    float* c6p = f;            f += n5;

    const long total_threads = (long)n_rays * 64;
    const int block = 256;
    const int grid = (int)((total_threads + block - 1) / block);

    k1<<<grid, block, 0, stream>>>(rgb_pred, rgb_target, opacity, ws, ts,
                                   out, T1w, T1p, n_rays);
    k2<<<1, 1024, 0, stream>>>(T1w, T1p, c2w, c2p, T2w, T2p, c3w, c3p,
                               T3w, T3p, c4w, c4p, T4w, T4p, c5w, c5p,
                               T5w, T5p, c6w, c6p, n1);
    k3<<<grid, block, 0, stream>>>(ws, ts, deltas, T1w, T1p, c2w, c2p,
                                   out, n_rays);
}